// Round 9
// baseline (528.556 us; speedup 1.0000x reference)
//
#include <hip/hip_runtime.h>

// GraphProp: N nodes, E edges, H=128, T rounds.
// a[v] = deg(v)*(Wd@hv+bmsg) + Ws@s[v] + g[v]*we  (linearity of segment_sum)
// gi = Wih@a folds into Wbig: ONE GEMM per round G[v] = Wbig @ x[v],
//   x = [deg*hv | s | hv] (384), Wbig [512x384] fragment-interleaved.
// fp16 everywhere (bf16 failed absmax 0.39 > 0.096; fp16 gives 0.052).
// Round-9: (1) csr_count keeps ONLY the int count atomic (he summed in prep
// from he_sorted -> halves the 1.6M device-scope atomics, each of which
// write-through a 64B line); (2) multi-block scan (old single-block scan
// used 1 of 256 CUs); (3) fused GEMM 64 rows/block (halves B-operand L2
// re-read traffic; B=384KB/block regardless of rows).

using f16x8 = __attribute__((ext_vector_type(8))) _Float16;
using f32x4 = __attribute__((ext_vector_type(4))) float;

struct h2 { _Float16 x, y; };
struct h4 { _Float16 a, b, c, d; };

// ---- Wbig build (once per call): fp16 weights (interleaved) + fp32 cvec ----
// WbigF element for (col o, k): p=o>>7, w=(o>>5)&3, j=(o>>4)&1, lr=o&15;
// k0c=k>>5, lkg=(k>>3)&3, kin=k&7;
// idx = (((k0c*4 + w)*4 + p)*2 + j)*512 + (lkg*16 + lr)*8 + kin
__global__ void build_wbig_kernel(const float* __restrict__ Wih,
                                  const float* __restrict__ Whh,
                                  const float* __restrict__ Wmsg,
                                  const float* __restrict__ bmsg,
                                  _Float16* __restrict__ WbigF,
                                  float* __restrict__ cvec) {
  int c = blockIdx.x * blockDim.x + threadIdx.x;  // 0..385 (384=c1, 385=c2)
  int o = blockIdx.y;                             // 0..511
  int t = blockIdx.z;
  if (c >= 386) return;
  const float* wih  = Wih  + (size_t)t * 384 * 256;
  const float* whh  = Whh  + (size_t)t * 384 * 128;
  const float* wmsg = Wmsg + (size_t)t * 256 * 257;
  const float* bm   = bmsg + (size_t)t * 256;
  _Float16* wb = WbigF + (size_t)t * 512 * 384;
  float* cv = cvec + (size_t)t * 768;
  if (c < 384) {
    float val = 0.0f;
    if (c < 256) {
      if (o < 384) {                 // A1|A2 = Wih @ Wmsg[:, 0:256]
        float acc = 0.0f;
        for (int k = 0; k < 256; ++k) acc += wih[(size_t)o * 256 + k] * wmsg[(size_t)k * 257 + c];
        val = acc;
      }
    } else {
      if (o < 256)       val = whh[(size_t)o * 128 + (c - 256)];
      else if (o >= 384) val = whh[(size_t)(256 + o - 384) * 128 + (c - 256)];
    }
    int p = o >> 7, w = (o >> 5) & 3, j = (o >> 4) & 1, lr = o & 15;
    int k0c = c >> 5, lkg = (c >> 3) & 3, kin = c & 7;
    size_t idx = (size_t)((((k0c * 4 + w) * 4 + p) * 2 + j)) * 512 + (lkg * 16 + lr) * 8 + kin;
    wb[idx] = (_Float16)val;
  } else if (o < 384) {
    float acc = 0.0f;
    if (c == 384) {
      for (int k = 0; k < 256; ++k) acc += wih[(size_t)o * 256 + k] * bm[k];
      cv[o] = acc;                   // c1
    } else {
      for (int k = 0; k < 256; ++k) acc += wih[(size_t)o * 256 + k] * wmsg[(size_t)k * 257 + 256];
      cv[384 + o] = acc;             // c2
    }
  }
}

// ---- CSR build (once per call) ----
__global__ void csr_count_kernel(const int* __restrict__ dst,
                                 int* __restrict__ counts, int E) {
  int e = blockIdx.x * blockDim.x + threadIdx.x;
  if (e >= E) return;
  atomicAdd(&counts[dst[e]], 1);
}

// scan pass 1: per-1024-chunk totals
__global__ __launch_bounds__(1024) void scan_reduce_kernel(const int* __restrict__ counts,
                                                           int* __restrict__ partial, int N) {
  __shared__ int wsum[16];
  int i = blockIdx.x * 1024 + threadIdx.x;
  int x = (i < N) ? counts[i] : 0;
#pragma unroll
  for (int off = 32; off; off >>= 1) x += __shfl_down(x, off);
  int lane = threadIdx.x & 63, w = threadIdx.x >> 6;
  if (lane == 0) wsum[w] = x;
  __syncthreads();
  if (threadIdx.x < 16) {
    int y = wsum[threadIdx.x];
#pragma unroll
    for (int off = 8; off; off >>= 1) y += __shfl_down(y, off);
    if (threadIdx.x == 0) partial[blockIdx.x] = y;
  }
}

// scan pass 2: exclusive scan of NB partials (single wave, looped)
__global__ void scan_small_kernel(int* __restrict__ partial, int NB) {
  int lane = threadIdx.x;  // 64 threads
  int carry = 0;
  for (int base = 0; base < NB; base += 64) {
    int x = (base + lane < NB) ? partial[base + lane] : 0;
    int incl = x;
#pragma unroll
    for (int off = 1; off < 64; off <<= 1) {
      int y = __shfl_up(incl, off);
      if (lane >= off) incl += y;
    }
    int tot = __shfl(incl, 63);
    if (base + lane < NB) partial[base + lane] = incl - x + carry;
    carry += tot;
  }
}

// scan pass 3: per-chunk scan + chunk offset -> row_start, cursor
__global__ __launch_bounds__(1024) void scan_apply_kernel(const int* __restrict__ counts,
                                                          const int* __restrict__ partial,
                                                          int* __restrict__ row_start,
                                                          int* __restrict__ cursor,
                                                          int N, int E) {
  __shared__ int wtot[16];
  __shared__ int woff[16];
  int i = blockIdx.x * 1024 + threadIdx.x;
  int lane = threadIdx.x & 63, w = threadIdx.x >> 6;
  int x = (i < N) ? counts[i] : 0;
  int incl = x;
#pragma unroll
  for (int off = 1; off < 64; off <<= 1) {
    int y = __shfl_up(incl, off);
    if (lane >= off) incl += y;
  }
  if (lane == 63) wtot[w] = incl;
  __syncthreads();
  if (w == 0 && lane < 16) {
    int wv = wtot[lane];
    int wincl = wv;
#pragma unroll
    for (int off = 1; off < 16; off <<= 1) {
      int y = __shfl_up(wincl, off);
      if (lane >= off) wincl += y;
    }
    woff[lane] = wincl - wv;
  }
  __syncthreads();
  int excl = incl - x + woff[w] + partial[blockIdx.x];
  if (i < N) { row_start[i] = excl; cursor[i] = excl; }  // cursor==counts alias:
  if (i == 0) row_start[N] = E;                          // own-idx read-then-write, safe
}

__global__ void csr_bucket_kernel(const int* __restrict__ src,
                                  const int* __restrict__ dst,
                                  const float* __restrict__ he,
                                  int* __restrict__ cursor,
                                  int* __restrict__ srcs_sorted,
                                  float* __restrict__ he_sorted, int E) {
  int e = blockIdx.x * blockDim.x + threadIdx.x;
  if (e >= E) return;
  int pos = atomicAdd(&cursor[dst[e]], 1);
  srcs_sorted[pos] = src[e];
  he_sorted[pos] = he[e];
}

// ---- per round: hv fp32 -> hb fp16 ----
__global__ void convert_kernel(const float* __restrict__ hv,
                               _Float16* __restrict__ hb, int total4) {
  int i = blockIdx.x * blockDim.x + threadIdx.x;
  if (i >= total4) return;
  float4 v = *reinterpret_cast<const float4*>(hv + (size_t)i * 4);
  h4 o;
  o.a = (_Float16)v.x; o.b = (_Float16)v.y; o.c = (_Float16)v.z; o.d = (_Float16)v.w;
  *reinterpret_cast<h4*>(hb + (size_t)i * 4) = o;
}

// ---- per round: gather s[v]=sum hb[src], g[v]=sum he (no atomics);
//      write xbF fragment-interleaved ----
__global__ __launch_bounds__(256) void prep_kernel(const _Float16* __restrict__ hb,
                                                   const int* __restrict__ row_start,
                                                   const int* __restrict__ srcs_sorted,
                                                   const float* __restrict__ he_sorted,
                                                   _Float16* __restrict__ xbF,
                                                   float* __restrict__ deg,
                                                   float* __restrict__ g, int N) {
  int w = threadIdx.x >> 6;
  int lane = threadIdx.x & 63;
  int v = blockIdx.x * 4 + w;
  if (v >= N) return;
  int r0 = row_start[v];
  int r1 = row_start[v + 1];
  float ax = 0.f, ay = 0.f, hes = 0.f;
  for (int base = r0; base < r1; base += 64) {
    int nn = min(64, r1 - base);
    int myv = (lane < nn) ? srcs_sorted[base + lane] : 0;
    hes += (lane < nn) ? he_sorted[base + lane] : 0.f;
    int j = 0;
    for (; j + 4 <= nn; j += 4) {
      int s0 = __shfl(myv, j + 0), s1 = __shfl(myv, j + 1);
      int s2 = __shfl(myv, j + 2), s3 = __shfl(myv, j + 3);
      h2 u0 = *reinterpret_cast<const h2*>(hb + (size_t)s0 * 128 + lane * 2);
      h2 u1 = *reinterpret_cast<const h2*>(hb + (size_t)s1 * 128 + lane * 2);
      h2 u2 = *reinterpret_cast<const h2*>(hb + (size_t)s2 * 128 + lane * 2);
      h2 u3 = *reinterpret_cast<const h2*>(hb + (size_t)s3 * 128 + lane * 2);
      ax += (float)u0.x + (float)u1.x + (float)u2.x + (float)u3.x;
      ay += (float)u0.y + (float)u1.y + (float)u2.y + (float)u3.y;
    }
    for (; j < nn; ++j) {
      int sv = __shfl(myv, j);
      h2 u = *reinterpret_cast<const h2*>(hb + (size_t)sv * 128 + lane * 2);
      ax += (float)u.x; ay += (float)u.y;
    }
  }
#pragma unroll
  for (int off = 32; off; off >>= 1) hes += __shfl_xor(hes, off);
  float d = (float)(r1 - r0);
  h2 hu = *reinterpret_cast<const h2*>(hb + (size_t)v * 128 + lane * 2);
  h2 dh; dh.x = (_Float16)(d * (float)hu.x); dh.y = (_Float16)(d * (float)hu.y);
  h2 ss; ss.x = (_Float16)ax; ss.y = (_Float16)ay;
  int mt = v >> 4, lrv = v & 15;
  _Float16* xmt = xbF + (size_t)mt * 12 * 512;
  auto store2 = [&](int c, h2 val) {
    int k0c = c >> 5, lkg = (c >> 3) & 3, kin = c & 7;
    _Float16* p = xmt + (size_t)k0c * 512 + (lkg * 16 + lrv) * 8 + kin;
    *reinterpret_cast<h2*>(p) = val;
  };
  store2(lane * 2, dh);            // plane 0: deg*h   (x-cols 0..127)
  store2(128 + lane * 2, ss);      // plane 1: s       (x-cols 128..255)
  store2(256 + lane * 2, hu);      // plane 2: h       (x-cols 256..383)
  if (lane == 0) { deg[v] = d; g[v] = hes; }
}

// ---- fused GEMM (fp16 MFMA) + GRU gate epilogue ----
// Block = 64 rows x 512 cols, 4 waves; wave w covers cols p*128+w*32+j*16+lr.
// All fragment loads are base+lane*16 contiguous 1KB bursts.
__global__ __launch_bounds__(256, 1) void fused_gemm_gate_kernel(
    const _Float16* __restrict__ xbF,
    const _Float16* __restrict__ wbigF,
    const float* __restrict__ deg, const float* __restrict__ gv,
    const float* __restrict__ cvec,
    const float* __restrict__ bih, const float* __restrict__ bhh,
    const float* __restrict__ hv_in, float* __restrict__ hv_out, int M) {
  int wave = threadIdx.x >> 6;
  int lane = threadIdx.x & 63;
  int m0 = blockIdx.x * 64;
  int Mt = (M + 15) >> 4;

  f32x4 acc[4][2][4];  // [m][j][p]
#pragma unroll
  for (int m = 0; m < 4; ++m)
#pragma unroll
    for (int j = 0; j < 2; ++j)
#pragma unroll
      for (int p = 0; p < 4; ++p) acc[m][j][p] = (f32x4){0.f, 0.f, 0.f, 0.f};

  const _Float16* ap[4];
#pragma unroll
  for (int m = 0; m < 4; ++m) {
    int mt = min(m0 / 16 + m, Mt - 1);
    ap[m] = xbF + (size_t)mt * 12 * 512 + lane * 8;
  }
  // B elem: (((k0c*4 + w)*4 + p)*2 + j)*512 + lane*8
  const _Float16* bp = wbigF + (size_t)wave * 4096 + lane * 8;

  for (int k0c = 0; k0c < 12; ++k0c) {
    f16x8 a[4];
#pragma unroll
    for (int m = 0; m < 4; ++m)
      a[m] = *reinterpret_cast<const f16x8*>(ap[m] + (size_t)k0c * 512);
    const _Float16* bk = bp + (size_t)k0c * 16384;
#pragma unroll
    for (int p = 0; p < 4; ++p) {
#pragma unroll
      for (int j = 0; j < 2; ++j) {
        f16x8 b = *reinterpret_cast<const f16x8*>(bk + (p * 2 + j) * 512);
#pragma unroll
        for (int m = 0; m < 4; ++m)
          acc[m][j][p] = __builtin_amdgcn_mfma_f32_16x16x32_f16(a[m], b, acc[m][j][p], 0, 0, 0);
      }
    }
  }

  // epilogue: C layout col=lane&15, row=(lane>>4)*4+reg (m89-verified)
  int lr = lane & 15;
  int j0 = wave * 32;
#pragma unroll
  for (int j = 0; j < 2; ++j) {
    int jj = j0 + j * 16 + lr;          // 0..127
    float cv0 = cvec[jj], cv1 = cvec[128 + jj], cv2 = cvec[256 + jj];
    float cg0 = cvec[384 + jj], cg1 = cvec[512 + jj], cg2 = cvec[640 + jj];
    float b0 = bih[jj] + bhh[jj];
    float b1 = bih[128 + jj] + bhh[128 + jj];
    float b2 = bih[256 + jj];
    float b3 = bhh[256 + jj];
#pragma unroll
    for (int m = 0; m < 4; ++m) {
#pragma unroll
      for (int reg = 0; reg < 4; ++reg) {
        int v = m0 + m * 16 + (lane >> 4) * 4 + reg;
        if (v >= M) continue;
        float d = deg[v], gg = gv[v];
        float pre_r = acc[m][j][0][reg] + d * cv0 + gg * cg0 + b0;
        float pre_z = acc[m][j][1][reg] + d * cv1 + gg * cg1 + b1;
        float i_n   = acc[m][j][2][reg] + d * cv2 + gg * cg2 + b2;
        float h_n   = acc[m][j][3][reg] + b3;
        float r = 1.0f / (1.0f + expf(-pre_r));
        float z = 1.0f / (1.0f + expf(-pre_z));
        float n = tanhf(i_n + r * h_n);
        float h = hv_in[(size_t)v * 128 + jj];
        hv_out[(size_t)v * 128 + jj] = (1.0f - z) * n + z * h;
      }
    }
  }
}

extern "C" void kernel_launch(void* const* d_in, const int* in_sizes, int n_in,
                              void* d_out, int out_size, void* d_ws, size_t ws_size,
                              hipStream_t stream) {
  const float* hv0  = (const float*)d_in[0];
  const float* he   = (const float*)d_in[1];
  const int*   src  = (const int*)d_in[2];
  const int*   dst  = (const int*)d_in[3];
  const float* Wmsg = (const float*)d_in[4];
  const float* bmsg = (const float*)d_in[5];
  const float* Wih  = (const float*)d_in[6];
  const float* Whh  = (const float*)d_in[7];
  const float* bih  = (const float*)d_in[8];
  const float* bhh  = (const float*)d_in[9];

  int N = in_sizes[0] / 128;
  int E = in_sizes[1];
  int T = in_sizes[4] / (256 * 257);
  int Mt = (N + 15) / 16;
  int NB = (N + 1023) / 1024;

  size_t off = 0;
  auto alloc = [&](size_t bytes) { size_t o = off; off += (bytes + 15) & ~(size_t)15; return o; };
  size_t o_hb   = alloc((size_t)N * 128 * 2);
  size_t o_xb   = alloc((size_t)Mt * 12 * 512 * 2);
  size_t o_deg  = alloc((size_t)N * 4);
  size_t o_g    = alloc((size_t)N * 4);
  size_t o_cv   = alloc((size_t)T * 768 * 4);
  size_t o_wb   = alloc((size_t)T * 512 * 384 * 2);
  size_t o_rs   = alloc((size_t)(N + 1) * 4);
  size_t o_ss   = alloc((size_t)E * 4);
  size_t o_he   = alloc((size_t)E * 4);
  size_t o_pt   = alloc((size_t)NB * 4);
  if (ws_size < off) return;  // clean failure instead of OOB crash

  char* wsb = (char*)d_ws;
  _Float16* hb     = (_Float16*)(wsb + o_hb);
  _Float16* xbF    = (_Float16*)(wsb + o_xb);
  float* deg       = (float*)(wsb + o_deg);
  float* g         = (float*)(wsb + o_g);
  float* cvec      = (float*)(wsb + o_cv);
  _Float16* wbigF  = (_Float16*)(wsb + o_wb);
  int* row_start   = (int*)(wsb + o_rs);
  int* srcs_sorted = (int*)(wsb + o_ss);
  float* he_sorted = (float*)(wsb + o_he);
  int* partial     = (int*)(wsb + o_pt);
  int* cursor      = (int*)xbF;  // scratch during CSR build only
  float* out = (float*)d_out;

  {
    dim3 gb((386 + 63) / 64, 512, T);
    build_wbig_kernel<<<gb, 64, 0, stream>>>(Wih, Whh, Wmsg, bmsg, wbigF, cvec);
  }

  hipMemsetAsync(cursor, 0, (size_t)N * sizeof(int), stream);
  csr_count_kernel<<<(E + 255) / 256, 256, 0, stream>>>(dst, cursor, E);
  scan_reduce_kernel<<<NB, 1024, 0, stream>>>(cursor, partial, N);
  scan_small_kernel<<<1, 64, 0, stream>>>(partial, NB);
  scan_apply_kernel<<<NB, 1024, 0, stream>>>(cursor, partial, row_start, cursor, N, E);
  csr_bucket_kernel<<<(E + 255) / 256, 256, 0, stream>>>(src, dst, he, cursor,
                                                         srcs_sorted, he_sorted, E);

  for (int t = 0; t < T; ++t) {
    const float* hv_in = (t == 0) ? hv0 : out;
    int total4 = N * 128 / 4;
    convert_kernel<<<(total4 + 255) / 256, 256, 0, stream>>>(hv_in, hb, total4);
    prep_kernel<<<(N + 3) / 4, 256, 0, stream>>>(hb, row_start, srcs_sorted, he_sorted,
                                                 xbF, deg, g, N);
    fused_gemm_gate_kernel<<<(N + 63) / 64, 256, 0, stream>>>(
        xbF, wbigF + (size_t)t * 512 * 384, deg, g, cvec + (size_t)t * 768,
        bih + (size_t)t * 384, bhh + (size_t)t * 384, hv_in, out, N);
  }
}

// Round 10
// 430.986 us; speedup vs baseline: 1.2264x; 1.2264x over previous
//
#include <hip/hip_runtime.h>

// GraphProp: N nodes, E edges, H=128, T rounds.
// a[v] = deg(v)*(Wd@hv+bmsg) + Ws@s[v] + g[v]*we  (linearity of segment_sum)
// gi = Wih@a folds into Wbig: ONE GEMM per round G[v] = Wbig @ x[v],
//   x = [deg*hv | s | hv] (384), Wbig [512x384] fragment-interleaved.
// fp16 everywhere (bf16 failed absmax 0.39 > 0.096; fp16 gives 0.052).
// Round-10: fused GEMM restructured wave-per-(16-row m-tile x 32-col group).
// r9's 64-row block (136 VGPR, occupancy 8.8%) regressed 79->127us; now
// acc=32 VGPR/wave, block=8 waves sharing ONE col-group so all waves read
// identical B fragments (L1 broadcast), grid has 12.5K waves for latency
// hiding. B L2 traffic 600->150MB, A 38->150MB (net ~300 vs 638).

using f16x8 = __attribute__((ext_vector_type(8))) _Float16;
using f32x4 = __attribute__((ext_vector_type(4))) float;

struct h2 { _Float16 x, y; };
struct h4 { _Float16 a, b, c, d; };

// ---- Wbig build (once per call): fp16 weights (interleaved) + fp32 cvec ----
// WbigF element for (col o, k): p=o>>7, w=(o>>5)&3, j=(o>>4)&1, lr=o&15;
// k0c=k>>5, lkg=(k>>3)&3, kin=k&7;
// idx = (((k0c*4 + w)*4 + p)*2 + j)*512 + (lkg*16 + lr)*8 + kin
__global__ void build_wbig_kernel(const float* __restrict__ Wih,
                                  const float* __restrict__ Whh,
                                  const float* __restrict__ Wmsg,
                                  const float* __restrict__ bmsg,
                                  _Float16* __restrict__ WbigF,
                                  float* __restrict__ cvec) {
  int c = blockIdx.x * blockDim.x + threadIdx.x;  // 0..385 (384=c1, 385=c2)
  int o = blockIdx.y;                             // 0..511
  int t = blockIdx.z;
  if (c >= 386) return;
  const float* wih  = Wih  + (size_t)t * 384 * 256;
  const float* whh  = Whh  + (size_t)t * 384 * 128;
  const float* wmsg = Wmsg + (size_t)t * 256 * 257;
  const float* bm   = bmsg + (size_t)t * 256;
  _Float16* wb = WbigF + (size_t)t * 512 * 384;
  float* cv = cvec + (size_t)t * 768;
  if (c < 384) {
    float val = 0.0f;
    if (c < 256) {
      if (o < 384) {                 // A1|A2 = Wih @ Wmsg[:, 0:256]
        float acc = 0.0f;
        for (int k = 0; k < 256; ++k) acc += wih[(size_t)o * 256 + k] * wmsg[(size_t)k * 257 + c];
        val = acc;
      }
    } else {
      if (o < 256)       val = whh[(size_t)o * 128 + (c - 256)];
      else if (o >= 384) val = whh[(size_t)(256 + o - 384) * 128 + (c - 256)];
    }
    int p = o >> 7, w = (o >> 5) & 3, j = (o >> 4) & 1, lr = o & 15;
    int k0c = c >> 5, lkg = (c >> 3) & 3, kin = c & 7;
    size_t idx = (size_t)((((k0c * 4 + w) * 4 + p) * 2 + j)) * 512 + (lkg * 16 + lr) * 8 + kin;
    wb[idx] = (_Float16)val;
  } else if (o < 384) {
    float acc = 0.0f;
    if (c == 384) {
      for (int k = 0; k < 256; ++k) acc += wih[(size_t)o * 256 + k] * bm[k];
      cv[o] = acc;                   // c1
    } else {
      for (int k = 0; k < 256; ++k) acc += wih[(size_t)o * 256 + k] * wmsg[(size_t)k * 257 + 256];
      cv[384 + o] = acc;             // c2
    }
  }
}

// ---- CSR build (once per call) ----
__global__ void csr_count_kernel(const int* __restrict__ dst,
                                 int* __restrict__ counts, int E) {
  int e = blockIdx.x * blockDim.x + threadIdx.x;
  if (e >= E) return;
  atomicAdd(&counts[dst[e]], 1);
}

// scan pass 1: per-1024-chunk totals
__global__ __launch_bounds__(1024) void scan_reduce_kernel(const int* __restrict__ counts,
                                                           int* __restrict__ partial, int N) {
  __shared__ int wsum[16];
  int i = blockIdx.x * 1024 + threadIdx.x;
  int x = (i < N) ? counts[i] : 0;
#pragma unroll
  for (int off = 32; off; off >>= 1) x += __shfl_down(x, off);
  int lane = threadIdx.x & 63, w = threadIdx.x >> 6;
  if (lane == 0) wsum[w] = x;
  __syncthreads();
  if (threadIdx.x < 16) {
    int y = wsum[threadIdx.x];
#pragma unroll
    for (int off = 8; off; off >>= 1) y += __shfl_down(y, off);
    if (threadIdx.x == 0) partial[blockIdx.x] = y;
  }
}

// scan pass 2: exclusive scan of NB partials (single wave, looped)
__global__ void scan_small_kernel(int* __restrict__ partial, int NB) {
  int lane = threadIdx.x;  // 64 threads
  int carry = 0;
  for (int base = 0; base < NB; base += 64) {
    int x = (base + lane < NB) ? partial[base + lane] : 0;
    int incl = x;
#pragma unroll
    for (int off = 1; off < 64; off <<= 1) {
      int y = __shfl_up(incl, off);
      if (lane >= off) incl += y;
    }
    int tot = __shfl(incl, 63);
    if (base + lane < NB) partial[base + lane] = incl - x + carry;
    carry += tot;
  }
}

// scan pass 3: per-chunk scan + chunk offset -> row_start, cursor
__global__ __launch_bounds__(1024) void scan_apply_kernel(const int* __restrict__ counts,
                                                          const int* __restrict__ partial,
                                                          int* __restrict__ row_start,
                                                          int* __restrict__ cursor,
                                                          int N, int E) {
  __shared__ int wtot[16];
  __shared__ int woff[16];
  int i = blockIdx.x * 1024 + threadIdx.x;
  int lane = threadIdx.x & 63, w = threadIdx.x >> 6;
  int x = (i < N) ? counts[i] : 0;
  int incl = x;
#pragma unroll
  for (int off = 1; off < 64; off <<= 1) {
    int y = __shfl_up(incl, off);
    if (lane >= off) incl += y;
  }
  if (lane == 63) wtot[w] = incl;
  __syncthreads();
  if (w == 0 && lane < 16) {
    int wv = wtot[lane];
    int wincl = wv;
#pragma unroll
    for (int off = 1; off < 16; off <<= 1) {
      int y = __shfl_up(wincl, off);
      if (lane >= off) wincl += y;
    }
    woff[lane] = wincl - wv;
  }
  __syncthreads();
  int excl = incl - x + woff[w] + partial[blockIdx.x];
  if (i < N) { row_start[i] = excl; cursor[i] = excl; }  // cursor==counts alias:
  if (i == 0) row_start[N] = E;                          // own-idx read-then-write, safe
}

__global__ void csr_bucket_kernel(const int* __restrict__ src,
                                  const int* __restrict__ dst,
                                  const float* __restrict__ he,
                                  int* __restrict__ cursor,
                                  int* __restrict__ srcs_sorted,
                                  float* __restrict__ he_sorted, int E) {
  int e = blockIdx.x * blockDim.x + threadIdx.x;
  if (e >= E) return;
  int pos = atomicAdd(&cursor[dst[e]], 1);
  srcs_sorted[pos] = src[e];
  he_sorted[pos] = he[e];
}

// ---- per round: hv fp32 -> hb fp16 ----
__global__ void convert_kernel(const float* __restrict__ hv,
                               _Float16* __restrict__ hb, int total4) {
  int i = blockIdx.x * blockDim.x + threadIdx.x;
  if (i >= total4) return;
  float4 v = *reinterpret_cast<const float4*>(hv + (size_t)i * 4);
  h4 o;
  o.a = (_Float16)v.x; o.b = (_Float16)v.y; o.c = (_Float16)v.z; o.d = (_Float16)v.w;
  *reinterpret_cast<h4*>(hb + (size_t)i * 4) = o;
}

// ---- per round: gather s[v]=sum hb[src], g[v]=sum he (no atomics);
//      write xbF fragment-interleaved ----
__global__ __launch_bounds__(256) void prep_kernel(const _Float16* __restrict__ hb,
                                                   const int* __restrict__ row_start,
                                                   const int* __restrict__ srcs_sorted,
                                                   const float* __restrict__ he_sorted,
                                                   _Float16* __restrict__ xbF,
                                                   float* __restrict__ deg,
                                                   float* __restrict__ g, int N) {
  int w = threadIdx.x >> 6;
  int lane = threadIdx.x & 63;
  int v = blockIdx.x * 4 + w;
  if (v >= N) return;
  int r0 = row_start[v];
  int r1 = row_start[v + 1];
  float ax = 0.f, ay = 0.f, hes = 0.f;
  for (int base = r0; base < r1; base += 64) {
    int nn = min(64, r1 - base);
    int myv = (lane < nn) ? srcs_sorted[base + lane] : 0;
    hes += (lane < nn) ? he_sorted[base + lane] : 0.f;
    int j = 0;
    for (; j + 4 <= nn; j += 4) {
      int s0 = __shfl(myv, j + 0), s1 = __shfl(myv, j + 1);
      int s2 = __shfl(myv, j + 2), s3 = __shfl(myv, j + 3);
      h2 u0 = *reinterpret_cast<const h2*>(hb + (size_t)s0 * 128 + lane * 2);
      h2 u1 = *reinterpret_cast<const h2*>(hb + (size_t)s1 * 128 + lane * 2);
      h2 u2 = *reinterpret_cast<const h2*>(hb + (size_t)s2 * 128 + lane * 2);
      h2 u3 = *reinterpret_cast<const h2*>(hb + (size_t)s3 * 128 + lane * 2);
      ax += (float)u0.x + (float)u1.x + (float)u2.x + (float)u3.x;
      ay += (float)u0.y + (float)u1.y + (float)u2.y + (float)u3.y;
    }
    for (; j < nn; ++j) {
      int sv = __shfl(myv, j);
      h2 u = *reinterpret_cast<const h2*>(hb + (size_t)sv * 128 + lane * 2);
      ax += (float)u.x; ay += (float)u.y;
    }
  }
#pragma unroll
  for (int off = 32; off; off >>= 1) hes += __shfl_xor(hes, off);
  float d = (float)(r1 - r0);
  h2 hu = *reinterpret_cast<const h2*>(hb + (size_t)v * 128 + lane * 2);
  h2 dh; dh.x = (_Float16)(d * (float)hu.x); dh.y = (_Float16)(d * (float)hu.y);
  h2 ss; ss.x = (_Float16)ax; ss.y = (_Float16)ay;
  int mt = v >> 4, lrv = v & 15;
  _Float16* xmt = xbF + (size_t)mt * 12 * 512;
  auto store2 = [&](int c, h2 val) {
    int k0c = c >> 5, lkg = (c >> 3) & 3, kin = c & 7;
    _Float16* p = xmt + (size_t)k0c * 512 + (lkg * 16 + lrv) * 8 + kin;
    *reinterpret_cast<h2*>(p) = val;
  };
  store2(lane * 2, dh);            // plane 0: deg*h   (x-cols 0..127)
  store2(128 + lane * 2, ss);      // plane 1: s       (x-cols 128..255)
  store2(256 + lane * 2, hu);      // plane 2: h       (x-cols 256..383)
  if (lane == 0) { deg[v] = d; g[v] = hes; }
}

// ---- fused GEMM (fp16 MFMA) + GRU gate epilogue ----
// Wave = one 16-row m-tile x one 32-col group (all 4 gate planes).
// Block = 8 waves = 8 consecutive m-tiles, ONE col-group (blockIdx.y):
// all waves read identical B fragments -> L1 broadcast. acc = 32 VGPR.
__global__ __launch_bounds__(512) void fused_gemm_gate_kernel(
    const _Float16* __restrict__ xbF,
    const _Float16* __restrict__ wbigF,
    const float* __restrict__ deg, const float* __restrict__ gv,
    const float* __restrict__ cvec,
    const float* __restrict__ bih, const float* __restrict__ bhh,
    const float* __restrict__ hv_in, float* __restrict__ hv_out, int M) {
  int wave = threadIdx.x >> 6;
  int lane = threadIdx.x & 63;
  int Mt = (M + 15) >> 4;
  int mt = blockIdx.x * 8 + wave;
  int mtc = min(mt, Mt - 1);
  int cg = blockIdx.y;  // col-group: jj in [cg*32, cg*32+32)

  f32x4 acc[2][4];  // [j][p]
#pragma unroll
  for (int j = 0; j < 2; ++j)
#pragma unroll
    for (int p = 0; p < 4; ++p) acc[j][p] = (f32x4){0.f, 0.f, 0.f, 0.f};

  const _Float16* ap = xbF + (size_t)mtc * 12 * 512 + lane * 8;
  // B elem: (((k0c*4 + cg)*4 + p)*2 + j)*512 + lane*8
  const _Float16* bp = wbigF + (size_t)cg * 4096 + lane * 8;

  for (int k0c = 0; k0c < 12; ++k0c) {
    f16x8 a = *reinterpret_cast<const f16x8*>(ap + (size_t)k0c * 512);
    const _Float16* bk = bp + (size_t)k0c * 16384;
#pragma unroll
    for (int p = 0; p < 4; ++p) {
#pragma unroll
      for (int j = 0; j < 2; ++j) {
        f16x8 b = *reinterpret_cast<const f16x8*>(bk + (p * 2 + j) * 512);
        acc[j][p] = __builtin_amdgcn_mfma_f32_16x16x32_f16(a, b, acc[j][p], 0, 0, 0);
      }
    }
  }

  // epilogue: C layout col=lane&15, row=(lane>>4)*4+reg (m89-verified)
  int lr = lane & 15;
#pragma unroll
  for (int j = 0; j < 2; ++j) {
    int jj = cg * 32 + j * 16 + lr;          // 0..127
    float cv0 = cvec[jj], cv1 = cvec[128 + jj], cv2 = cvec[256 + jj];
    float cg0 = cvec[384 + jj], cg1 = cvec[512 + jj], cg2 = cvec[640 + jj];
    float b0 = bih[jj] + bhh[jj];
    float b1 = bih[128 + jj] + bhh[128 + jj];
    float b2 = bih[256 + jj];
    float b3 = bhh[256 + jj];
#pragma unroll
    for (int reg = 0; reg < 4; ++reg) {
      int v = mt * 16 + (lane >> 4) * 4 + reg;
      if (mt >= Mt || v >= M) continue;
      float d = deg[v], gg = gv[v];
      float pre_r = acc[j][0][reg] + d * cv0 + gg * cg0 + b0;
      float pre_z = acc[j][1][reg] + d * cv1 + gg * cg1 + b1;
      float i_n   = acc[j][2][reg] + d * cv2 + gg * cg2 + b2;
      float h_n   = acc[j][3][reg] + b3;
      float r = 1.0f / (1.0f + expf(-pre_r));
      float z = 1.0f / (1.0f + expf(-pre_z));
      float n = tanhf(i_n + r * h_n);
      float h = hv_in[(size_t)v * 128 + jj];
      hv_out[(size_t)v * 128 + jj] = (1.0f - z) * n + z * h;
    }
  }
}

extern "C" void kernel_launch(void* const* d_in, const int* in_sizes, int n_in,
                              void* d_out, int out_size, void* d_ws, size_t ws_size,
                              hipStream_t stream) {
  const float* hv0  = (const float*)d_in[0];
  const float* he   = (const float*)d_in[1];
  const int*   src  = (const int*)d_in[2];
  const int*   dst  = (const int*)d_in[3];
  const float* Wmsg = (const float*)d_in[4];
  const float* bmsg = (const float*)d_in[5];
  const float* Wih  = (const float*)d_in[6];
  const float* Whh  = (const float*)d_in[7];
  const float* bih  = (const float*)d_in[8];
  const float* bhh  = (const float*)d_in[9];

  int N = in_sizes[0] / 128;
  int E = in_sizes[1];
  int T = in_sizes[4] / (256 * 257);
  int Mt = (N + 15) / 16;
  int NB = (N + 1023) / 1024;

  size_t off = 0;
  auto alloc = [&](size_t bytes) { size_t o = off; off += (bytes + 15) & ~(size_t)15; return o; };
  size_t o_hb   = alloc((size_t)N * 128 * 2);
  size_t o_xb   = alloc((size_t)Mt * 12 * 512 * 2);
  size_t o_deg  = alloc((size_t)N * 4);
  size_t o_g    = alloc((size_t)N * 4);
  size_t o_cv   = alloc((size_t)T * 768 * 4);
  size_t o_wb   = alloc((size_t)T * 512 * 384 * 2);
  size_t o_rs   = alloc((size_t)(N + 1) * 4);
  size_t o_ss   = alloc((size_t)E * 4);
  size_t o_he   = alloc((size_t)E * 4);
  size_t o_pt   = alloc((size_t)NB * 4);
  if (ws_size < off) return;  // clean failure instead of OOB crash

  char* wsb = (char*)d_ws;
  _Float16* hb     = (_Float16*)(wsb + o_hb);
  _Float16* xbF    = (_Float16*)(wsb + o_xb);
  float* deg       = (float*)(wsb + o_deg);
  float* g         = (float*)(wsb + o_g);
  float* cvec      = (float*)(wsb + o_cv);
  _Float16* wbigF  = (_Float16*)(wsb + o_wb);
  int* row_start   = (int*)(wsb + o_rs);
  int* srcs_sorted = (int*)(wsb + o_ss);
  float* he_sorted = (float*)(wsb + o_he);
  int* partial     = (int*)(wsb + o_pt);
  int* cursor      = (int*)xbF;  // scratch during CSR build only
  float* out = (float*)d_out;

  {
    dim3 gb((386 + 63) / 64, 512, T);
    build_wbig_kernel<<<gb, 64, 0, stream>>>(Wih, Whh, Wmsg, bmsg, wbigF, cvec);
  }

  hipMemsetAsync(cursor, 0, (size_t)N * sizeof(int), stream);
  csr_count_kernel<<<(E + 255) / 256, 256, 0, stream>>>(dst, cursor, E);
  scan_reduce_kernel<<<NB, 1024, 0, stream>>>(cursor, partial, N);
  scan_small_kernel<<<1, 64, 0, stream>>>(partial, NB);
  scan_apply_kernel<<<NB, 1024, 0, stream>>>(cursor, partial, row_start, cursor, N, E);
  csr_bucket_kernel<<<(E + 255) / 256, 256, 0, stream>>>(src, dst, he, cursor,
                                                         srcs_sorted, he_sorted, E);

  for (int t = 0; t < T; ++t) {
    const float* hv_in = (t == 0) ? hv0 : out;
    int total4 = N * 128 / 4;
    convert_kernel<<<(total4 + 255) / 256, 256, 0, stream>>>(hv_in, hb, total4);
    prep_kernel<<<(N + 3) / 4, 256, 0, stream>>>(hb, row_start, srcs_sorted, he_sorted,
                                                 xbF, deg, g, N);
    dim3 gf((Mt + 7) / 8, 4);
    fused_gemm_gate_kernel<<<gf, 512, 0, stream>>>(
        xbF, wbigF + (size_t)t * 512 * 384, deg, g, cvec + (size_t)t * 768,
        bih + (size_t)t * 384, bhh + (size_t)t * 384, hv_in, out, N);
  }
}

// Round 12
// 427.849 us; speedup vs baseline: 1.2354x; 1.0073x over previous
//
#include <hip/hip_runtime.h>

// GraphProp: N nodes, E edges, H=128, T rounds.
// a[v] = deg(v)*(Wd@hv+bmsg) + Ws@s[v] + g[v]*we  (linearity of segment_sum)
// gi = Wih@a folds into Wbig: ONE GEMM per round G[v] = Wbig @ x[v],
//   x = [deg*hv | s | hv] (384), Wbig [512x384] fragment-interleaved.
// fp16 everywhere (bf16 failed absmax 0.39 > 0.096; fp16 gives 0.052).
// Round-12 (= r11 resubmit; infra failure): fast-math epilogue. r10 counters:
// VALUBusy 31.6% = 3x MfmaUtil 11.4% -> libm expf/tanhf dominate (~600 VALU
// instr/lane-set). Native v_exp/rcp forms cut that ~3x. GEMM structure
// unchanged (wave-per-mtile x 32-col group, 8 waves/block share B via L1).

using f16x8 = __attribute__((ext_vector_type(8))) _Float16;
using f32x4 = __attribute__((ext_vector_type(4))) float;

struct h2 { _Float16 x, y; };
struct h4 { _Float16 a, b, c, d; };

static __device__ __forceinline__ float fsig(float x) {
  return __fdividef(1.0f, 1.0f + __expf(-x));        // v_exp-based, ~1ulp
}
static __device__ __forceinline__ float ftanh(float y) {
  y = fminf(fmaxf(y, -15.0f), 15.0f);                // tanh(15)=1.0f exactly; avoids inf/inf
  float t = __expf(-2.0f * y);
  return __fdividef(1.0f - t, 1.0f + t);
}

// ---- Wbig build (once per call): fp16 weights (interleaved) + fp32 cvec ----
// WbigF element for (col o, k): p=o>>7, w=(o>>5)&3, j=(o>>4)&1, lr=o&15;
// k0c=k>>5, lkg=(k>>3)&3, kin=k&7;
// idx = (((k0c*4 + w)*4 + p)*2 + j)*512 + (lkg*16 + lr)*8 + kin
__global__ void build_wbig_kernel(const float* __restrict__ Wih,
                                  const float* __restrict__ Whh,
                                  const float* __restrict__ Wmsg,
                                  const float* __restrict__ bmsg,
                                  _Float16* __restrict__ WbigF,
                                  float* __restrict__ cvec) {
  int c = blockIdx.x * blockDim.x + threadIdx.x;  // 0..385 (384=c1, 385=c2)
  int o = blockIdx.y;                             // 0..511
  int t = blockIdx.z;
  if (c >= 386) return;
  const float* wih  = Wih  + (size_t)t * 384 * 256;
  const float* whh  = Whh  + (size_t)t * 384 * 128;
  const float* wmsg = Wmsg + (size_t)t * 256 * 257;
  const float* bm   = bmsg + (size_t)t * 256;
  _Float16* wb = WbigF + (size_t)t * 512 * 384;
  float* cv = cvec + (size_t)t * 768;
  if (c < 384) {
    float val = 0.0f;
    if (c < 256) {
      if (o < 384) {                 // A1|A2 = Wih @ Wmsg[:, 0:256]
        float acc = 0.0f;
        for (int k = 0; k < 256; ++k) acc += wih[(size_t)o * 256 + k] * wmsg[(size_t)k * 257 + c];
        val = acc;
      }
    } else {
      if (o < 256)       val = whh[(size_t)o * 128 + (c - 256)];
      else if (o >= 384) val = whh[(size_t)(256 + o - 384) * 128 + (c - 256)];
    }
    int p = o >> 7, w = (o >> 5) & 3, j = (o >> 4) & 1, lr = o & 15;
    int k0c = c >> 5, lkg = (c >> 3) & 3, kin = c & 7;
    size_t idx = (size_t)((((k0c * 4 + w) * 4 + p) * 2 + j)) * 512 + (lkg * 16 + lr) * 8 + kin;
    wb[idx] = (_Float16)val;
  } else if (o < 384) {
    float acc = 0.0f;
    if (c == 384) {
      for (int k = 0; k < 256; ++k) acc += wih[(size_t)o * 256 + k] * bm[k];
      cv[o] = acc;                   // c1
    } else {
      for (int k = 0; k < 256; ++k) acc += wih[(size_t)o * 256 + k] * wmsg[(size_t)k * 257 + 256];
      cv[384 + o] = acc;             // c2
    }
  }
}

// ---- CSR build (once per call) ----
__global__ void csr_count_kernel(const int* __restrict__ dst,
                                 int* __restrict__ counts, int E) {
  int e = blockIdx.x * blockDim.x + threadIdx.x;
  if (e >= E) return;
  atomicAdd(&counts[dst[e]], 1);
}

// scan pass 1: per-1024-chunk totals
__global__ __launch_bounds__(1024) void scan_reduce_kernel(const int* __restrict__ counts,
                                                           int* __restrict__ partial, int N) {
  __shared__ int wsum[16];
  int i = blockIdx.x * 1024 + threadIdx.x;
  int x = (i < N) ? counts[i] : 0;
#pragma unroll
  for (int off = 32; off; off >>= 1) x += __shfl_down(x, off);
  int lane = threadIdx.x & 63, w = threadIdx.x >> 6;
  if (lane == 0) wsum[w] = x;
  __syncthreads();
  if (threadIdx.x < 16) {
    int y = wsum[threadIdx.x];
#pragma unroll
    for (int off = 8; off; off >>= 1) y += __shfl_down(y, off);
    if (threadIdx.x == 0) partial[blockIdx.x] = y;
  }
}

// scan pass 2: exclusive scan of NB partials (single wave, looped)
__global__ void scan_small_kernel(int* __restrict__ partial, int NB) {
  int lane = threadIdx.x;  // 64 threads
  int carry = 0;
  for (int base = 0; base < NB; base += 64) {
    int x = (base + lane < NB) ? partial[base + lane] : 0;
    int incl = x;
#pragma unroll
    for (int off = 1; off < 64; off <<= 1) {
      int y = __shfl_up(incl, off);
      if (lane >= off) incl += y;
    }
    int tot = __shfl(incl, 63);
    if (base + lane < NB) partial[base + lane] = incl - x + carry;
    carry += tot;
  }
}

// scan pass 3: per-chunk scan + chunk offset -> row_start, cursor
__global__ __launch_bounds__(1024) void scan_apply_kernel(const int* __restrict__ counts,
                                                          const int* __restrict__ partial,
                                                          int* __restrict__ row_start,
                                                          int* __restrict__ cursor,
                                                          int N, int E) {
  __shared__ int wtot[16];
  __shared__ int woff[16];
  int i = blockIdx.x * 1024 + threadIdx.x;
  int lane = threadIdx.x & 63, w = threadIdx.x >> 6;
  int x = (i < N) ? counts[i] : 0;
  int incl = x;
#pragma unroll
  for (int off = 1; off < 64; off <<= 1) {
    int y = __shfl_up(incl, off);
    if (lane >= off) incl += y;
  }
  if (lane == 63) wtot[w] = incl;
  __syncthreads();
  if (w == 0 && lane < 16) {
    int wv = wtot[lane];
    int wincl = wv;
#pragma unroll
    for (int off = 1; off < 16; off <<= 1) {
      int y = __shfl_up(wincl, off);
      if (lane >= off) wincl += y;
    }
    woff[lane] = wincl - wv;
  }
  __syncthreads();
  int excl = incl - x + woff[w] + partial[blockIdx.x];
  if (i < N) { row_start[i] = excl; cursor[i] = excl; }  // cursor==counts alias:
  if (i == 0) row_start[N] = E;                          // own-idx read-then-write, safe
}

__global__ void csr_bucket_kernel(const int* __restrict__ src,
                                  const int* __restrict__ dst,
                                  const float* __restrict__ he,
                                  int* __restrict__ cursor,
                                  int* __restrict__ srcs_sorted,
                                  float* __restrict__ he_sorted, int E) {
  int e = blockIdx.x * blockDim.x + threadIdx.x;
  if (e >= E) return;
  int pos = atomicAdd(&cursor[dst[e]], 1);
  srcs_sorted[pos] = src[e];
  he_sorted[pos] = he[e];
}

// ---- per round: hv fp32 -> hb fp16 ----
__global__ void convert_kernel(const float* __restrict__ hv,
                               _Float16* __restrict__ hb, int total4) {
  int i = blockIdx.x * blockDim.x + threadIdx.x;
  if (i >= total4) return;
  float4 v = *reinterpret_cast<const float4*>(hv + (size_t)i * 4);
  h4 o;
  o.a = (_Float16)v.x; o.b = (_Float16)v.y; o.c = (_Float16)v.z; o.d = (_Float16)v.w;
  *reinterpret_cast<h4*>(hb + (size_t)i * 4) = o;
}

// ---- per round: gather s[v]=sum hb[src], g[v]=sum he (no atomics);
//      write xbF fragment-interleaved ----
__global__ __launch_bounds__(256) void prep_kernel(const _Float16* __restrict__ hb,
                                                   const int* __restrict__ row_start,
                                                   const int* __restrict__ srcs_sorted,
                                                   const float* __restrict__ he_sorted,
                                                   _Float16* __restrict__ xbF,
                                                   float* __restrict__ deg,
                                                   float* __restrict__ g, int N) {
  int w = threadIdx.x >> 6;
  int lane = threadIdx.x & 63;
  int v = blockIdx.x * 4 + w;
  if (v >= N) return;
  int r0 = row_start[v];
  int r1 = row_start[v + 1];
  float ax = 0.f, ay = 0.f, hes = 0.f;
  for (int base = r0; base < r1; base += 64) {
    int nn = min(64, r1 - base);
    int myv = (lane < nn) ? srcs_sorted[base + lane] : 0;
    hes += (lane < nn) ? he_sorted[base + lane] : 0.f;
    int j = 0;
    for (; j + 4 <= nn; j += 4) {
      int s0 = __shfl(myv, j + 0), s1 = __shfl(myv, j + 1);
      int s2 = __shfl(myv, j + 2), s3 = __shfl(myv, j + 3);
      h2 u0 = *reinterpret_cast<const h2*>(hb + (size_t)s0 * 128 + lane * 2);
      h2 u1 = *reinterpret_cast<const h2*>(hb + (size_t)s1 * 128 + lane * 2);
      h2 u2 = *reinterpret_cast<const h2*>(hb + (size_t)s2 * 128 + lane * 2);
      h2 u3 = *reinterpret_cast<const h2*>(hb + (size_t)s3 * 128 + lane * 2);
      ax += (float)u0.x + (float)u1.x + (float)u2.x + (float)u3.x;
      ay += (float)u0.y + (float)u1.y + (float)u2.y + (float)u3.y;
    }
    for (; j < nn; ++j) {
      int sv = __shfl(myv, j);
      h2 u = *reinterpret_cast<const h2*>(hb + (size_t)sv * 128 + lane * 2);
      ax += (float)u.x; ay += (float)u.y;
    }
  }
#pragma unroll
  for (int off = 32; off; off >>= 1) hes += __shfl_xor(hes, off);
  float d = (float)(r1 - r0);
  h2 hu = *reinterpret_cast<const h2*>(hb + (size_t)v * 128 + lane * 2);
  h2 dh; dh.x = (_Float16)(d * (float)hu.x); dh.y = (_Float16)(d * (float)hu.y);
  h2 ss; ss.x = (_Float16)ax; ss.y = (_Float16)ay;
  int mt = v >> 4, lrv = v & 15;
  _Float16* xmt = xbF + (size_t)mt * 12 * 512;
  auto store2 = [&](int c, h2 val) {
    int k0c = c >> 5, lkg = (c >> 3) & 3, kin = c & 7;
    _Float16* p = xmt + (size_t)k0c * 512 + (lkg * 16 + lrv) * 8 + kin;
    *reinterpret_cast<h2*>(p) = val;
  };
  store2(lane * 2, dh);            // plane 0: deg*h   (x-cols 0..127)
  store2(128 + lane * 2, ss);      // plane 1: s       (x-cols 128..255)
  store2(256 + lane * 2, hu);      // plane 2: h       (x-cols 256..383)
  if (lane == 0) { deg[v] = d; g[v] = hes; }
}

// ---- fused GEMM (fp16 MFMA) + GRU gate epilogue ----
// Wave = one 16-row m-tile x one 32-col group (all 4 gate planes).
// Block = 8 waves = 8 consecutive m-tiles, ONE col-group (blockIdx.y):
// all waves read identical B fragments -> L1 broadcast. acc = 32 VGPR.
__global__ __launch_bounds__(512) void fused_gemm_gate_kernel(
    const _Float16* __restrict__ xbF,
    const _Float16* __restrict__ wbigF,
    const float* __restrict__ deg, const float* __restrict__ gv,
    const float* __restrict__ cvec,
    const float* __restrict__ bih, const float* __restrict__ bhh,
    const float* __restrict__ hv_in, float* __restrict__ hv_out, int M) {
  int wave = threadIdx.x >> 6;
  int lane = threadIdx.x & 63;
  int Mt = (M + 15) >> 4;
  int mt = blockIdx.x * 8 + wave;
  int mtc = min(mt, Mt - 1);
  int cg = blockIdx.y;  // col-group: jj in [cg*32, cg*32+32)

  f32x4 acc[2][4];  // [j][p]
#pragma unroll
  for (int j = 0; j < 2; ++j)
#pragma unroll
    for (int p = 0; p < 4; ++p) acc[j][p] = (f32x4){0.f, 0.f, 0.f, 0.f};

  const _Float16* ap = xbF + (size_t)mtc * 12 * 512 + lane * 8;
  // B elem: (((k0c*4 + cg)*4 + p)*2 + j)*512 + lane*8
  const _Float16* bp = wbigF + (size_t)cg * 4096 + lane * 8;

  for (int k0c = 0; k0c < 12; ++k0c) {
    f16x8 a = *reinterpret_cast<const f16x8*>(ap + (size_t)k0c * 512);
    const _Float16* bk = bp + (size_t)k0c * 16384;
#pragma unroll
    for (int p = 0; p < 4; ++p) {
#pragma unroll
      for (int j = 0; j < 2; ++j) {
        f16x8 b = *reinterpret_cast<const f16x8*>(bk + (p * 2 + j) * 512);
        acc[j][p] = __builtin_amdgcn_mfma_f32_16x16x32_f16(a, b, acc[j][p], 0, 0, 0);
      }
    }
  }

  // epilogue: C layout col=lane&15, row=(lane>>4)*4+reg (m89-verified)
  int lr = lane & 15;
  float dr[4], gr[4];
#pragma unroll
  for (int reg = 0; reg < 4; ++reg) {
    int v = min(mt * 16 + (lane >> 4) * 4 + reg, M - 1);
    dr[reg] = deg[v]; gr[reg] = gv[v];
  }
#pragma unroll
  for (int j = 0; j < 2; ++j) {
    int jj = cg * 32 + j * 16 + lr;          // 0..127
    float cv0 = cvec[jj], cv1 = cvec[128 + jj], cv2 = cvec[256 + jj];
    float cg0 = cvec[384 + jj], cg1 = cvec[512 + jj], cg2 = cvec[640 + jj];
    float b0 = bih[jj] + bhh[jj];
    float b1 = bih[128 + jj] + bhh[128 + jj];
    float b2 = bih[256 + jj];
    float b3 = bhh[256 + jj];
#pragma unroll
    for (int reg = 0; reg < 4; ++reg) {
      int v = mt * 16 + (lane >> 4) * 4 + reg;
      if (mt >= Mt || v >= M) continue;
      float d = dr[reg], gg = gr[reg];
      float pre_r = acc[j][0][reg] + d * cv0 + gg * cg0 + b0;
      float pre_z = acc[j][1][reg] + d * cv1 + gg * cg1 + b1;
      float i_n   = acc[j][2][reg] + d * cv2 + gg * cg2 + b2;
      float h_n   = acc[j][3][reg] + b3;
      float r = fsig(pre_r);
      float z = fsig(pre_z);
      float n = ftanh(i_n + r * h_n);
      float h = hv_in[(size_t)v * 128 + jj];
      hv_out[(size_t)v * 128 + jj] = (1.0f - z) * n + z * h;
    }
  }
}

extern "C" void kernel_launch(void* const* d_in, const int* in_sizes, int n_in,
                              void* d_out, int out_size, void* d_ws, size_t ws_size,
                              hipStream_t stream) {
  const float* hv0  = (const float*)d_in[0];
  const float* he   = (const float*)d_in[1];
  const int*   src  = (const int*)d_in[2];
  const int*   dst  = (const int*)d_in[3];
  const float* Wmsg = (const float*)d_in[4];
  const float* bmsg = (const float*)d_in[5];
  const float* Wih  = (const float*)d_in[6];
  const float* Whh  = (const float*)d_in[7];
  const float* bih  = (const float*)d_in[8];
  const float* bhh  = (const float*)d_in[9];

  int N = in_sizes[0] / 128;
  int E = in_sizes[1];
  int T = in_sizes[4] / (256 * 257);
  int Mt = (N + 15) / 16;
  int NB = (N + 1023) / 1024;

  size_t off = 0;
  auto alloc = [&](size_t bytes) { size_t o = off; off += (bytes + 15) & ~(size_t)15; return o; };
  size_t o_hb   = alloc((size_t)N * 128 * 2);
  size_t o_xb   = alloc((size_t)Mt * 12 * 512 * 2);
  size_t o_deg  = alloc((size_t)N * 4);
  size_t o_g    = alloc((size_t)N * 4);
  size_t o_cv   = alloc((size_t)T * 768 * 4);
  size_t o_wb   = alloc((size_t)T * 512 * 384 * 2);
  size_t o_rs   = alloc((size_t)(N + 1) * 4);
  size_t o_ss   = alloc((size_t)E * 4);
  size_t o_he   = alloc((size_t)E * 4);
  size_t o_pt   = alloc((size_t)NB * 4);
  if (ws_size < off) return;  // clean failure instead of OOB crash

  char* wsb = (char*)d_ws;
  _Float16* hb     = (_Float16*)(wsb + o_hb);
  _Float16* xbF    = (_Float16*)(wsb + o_xb);
  float* deg       = (float*)(wsb + o_deg);
  float* g         = (float*)(wsb + o_g);
  float* cvec      = (float*)(wsb + o_cv);
  _Float16* wbigF  = (_Float16*)(wsb + o_wb);
  int* row_start   = (int*)(wsb + o_rs);
  int* srcs_sorted = (int*)(wsb + o_ss);
  float* he_sorted = (float*)(wsb + o_he);
  int* partial     = (int*)(wsb + o_pt);
  int* cursor      = (int*)xbF;  // scratch during CSR build only
  float* out = (float*)d_out;

  {
    dim3 gb((386 + 63) / 64, 512, T);
    build_wbig_kernel<<<gb, 64, 0, stream>>>(Wih, Whh, Wmsg, bmsg, wbigF, cvec);
  }

  hipMemsetAsync(cursor, 0, (size_t)N * sizeof(int), stream);
  csr_count_kernel<<<(E + 255) / 256, 256, 0, stream>>>(dst, cursor, E);
  scan_reduce_kernel<<<NB, 1024, 0, stream>>>(cursor, partial, N);
  scan_small_kernel<<<1, 64, 0, stream>>>(partial, NB);
  scan_apply_kernel<<<NB, 1024, 0, stream>>>(cursor, partial, row_start, cursor, N, E);
  csr_bucket_kernel<<<(E + 255) / 256, 256, 0, stream>>>(src, dst, he, cursor,
                                                         srcs_sorted, he_sorted, E);

  for (int t = 0; t < T; ++t) {
    const float* hv_in = (t == 0) ? hv0 : out;
    int total4 = N * 128 / 4;
    convert_kernel<<<(total4 + 255) / 256, 256, 0, stream>>>(hv_in, hb, total4);
    prep_kernel<<<(N + 3) / 4, 256, 0, stream>>>(hb, row_start, srcs_sorted, he_sorted,
                                                 xbF, deg, g, N);
    dim3 gf((Mt + 7) / 8, 4);
    fused_gemm_gate_kernel<<<gf, 512, 0, stream>>>(
        xbF, wbigF + (size_t)t * 512 * 384, deg, g, cvec + (size_t)t * 768,
        bih + (size_t)t * 384, bhh + (size_t)t * 384, hv_in, out, N);
  }
}

// Round 14
// 379.332 us; speedup vs baseline: 1.3934x; 1.1279x over previous
//
#include <hip/hip_runtime.h>

// GraphProp: N nodes, E edges, H=128, T rounds.
// a[v] = deg(v)*(Wd@hv+bmsg) + Ws@s[v] + g[v]*we  (linearity of segment_sum)
// gi = Wih@a folds into Wbig: ONE GEMM per round G[v] = Wbig @ x[v],
//   x = [deg*hv | s | hv] (384), Wbig [512x384] fragment-interleaved.
// fp16 everywhere (bf16 failed absmax 0.39 > 0.096; fp16 gives 0.052).
// Round-14 (= r13 resubmit; infra failure): B staged in LDS. r12 showed
// fast-math cut VALU 31.6->23.2% with ZERO time change -> not VALU-bound.
// Real limiter: B slice (96KB) > L1 (32KB), every wave re-reads B from L2
// (1.2GB/dispatch, ~35us per-XCD L2-BW floor). Now: block stages B in two
// 48KB LDS sweeps (3 blocks/CU), wave owns 2 m-tiles, epilogue emits fp16
// h' so convert runs only at t=0.

using f16x8 = __attribute__((ext_vector_type(8))) _Float16;
using f32x4 = __attribute__((ext_vector_type(4))) float;

struct h2 { _Float16 x, y; };
struct h4 { _Float16 a, b, c, d; };

static __device__ __forceinline__ float fsig(float x) {
  return __fdividef(1.0f, 1.0f + __expf(-x));        // v_exp-based, ~1ulp
}
static __device__ __forceinline__ float ftanh(float y) {
  y = fminf(fmaxf(y, -15.0f), 15.0f);                // tanh(15)=1.0f exactly
  float t = __expf(-2.0f * y);
  return __fdividef(1.0f - t, 1.0f + t);
}

// ---- Wbig build (once per call): fp16 weights (interleaved) + fp32 cvec ----
// WbigF element for (col o, k): p=o>>7, w=(o>>5)&3, j=(o>>4)&1, lr=o&15;
// k0c=k>>5, lkg=(k>>3)&3, kin=k&7;
// idx = (((k0c*4 + w)*4 + p)*2 + j)*512 + (lkg*16 + lr)*8 + kin
__global__ void build_wbig_kernel(const float* __restrict__ Wih,
                                  const float* __restrict__ Whh,
                                  const float* __restrict__ Wmsg,
                                  const float* __restrict__ bmsg,
                                  _Float16* __restrict__ WbigF,
                                  float* __restrict__ cvec) {
  int c = blockIdx.x * blockDim.x + threadIdx.x;  // 0..385 (384=c1, 385=c2)
  int o = blockIdx.y;                             // 0..511
  int t = blockIdx.z;
  if (c >= 386) return;
  const float* wih  = Wih  + (size_t)t * 384 * 256;
  const float* whh  = Whh  + (size_t)t * 384 * 128;
  const float* wmsg = Wmsg + (size_t)t * 256 * 257;
  const float* bm   = bmsg + (size_t)t * 256;
  _Float16* wb = WbigF + (size_t)t * 512 * 384;
  float* cv = cvec + (size_t)t * 768;
  if (c < 384) {
    float val = 0.0f;
    if (c < 256) {
      if (o < 384) {                 // A1|A2 = Wih @ Wmsg[:, 0:256]
        float acc = 0.0f;
        for (int k = 0; k < 256; ++k) acc += wih[(size_t)o * 256 + k] * wmsg[(size_t)k * 257 + c];
        val = acc;
      }
    } else {
      if (o < 256)       val = whh[(size_t)o * 128 + (c - 256)];
      else if (o >= 384) val = whh[(size_t)(256 + o - 384) * 128 + (c - 256)];
    }
    int p = o >> 7, w = (o >> 5) & 3, j = (o >> 4) & 1, lr = o & 15;
    int k0c = c >> 5, lkg = (c >> 3) & 3, kin = c & 7;
    size_t idx = (size_t)((((k0c * 4 + w) * 4 + p) * 2 + j)) * 512 + (lkg * 16 + lr) * 8 + kin;
    wb[idx] = (_Float16)val;
  } else if (o < 384) {
    float acc = 0.0f;
    if (c == 384) {
      for (int k = 0; k < 256; ++k) acc += wih[(size_t)o * 256 + k] * bm[k];
      cv[o] = acc;                   // c1
    } else {
      for (int k = 0; k < 256; ++k) acc += wih[(size_t)o * 256 + k] * wmsg[(size_t)k * 257 + 256];
      cv[384 + o] = acc;             // c2
    }
  }
}

// ---- CSR build (once per call) ----
__global__ void csr_count_kernel(const int* __restrict__ dst,
                                 int* __restrict__ counts, int E) {
  int e = blockIdx.x * blockDim.x + threadIdx.x;
  if (e >= E) return;
  atomicAdd(&counts[dst[e]], 1);
}

// scan pass 1: per-1024-chunk totals
__global__ __launch_bounds__(1024) void scan_reduce_kernel(const int* __restrict__ counts,
                                                           int* __restrict__ partial, int N) {
  __shared__ int wsum[16];
  int i = blockIdx.x * 1024 + threadIdx.x;
  int x = (i < N) ? counts[i] : 0;
#pragma unroll
  for (int off = 32; off; off >>= 1) x += __shfl_down(x, off);
  int lane = threadIdx.x & 63, w = threadIdx.x >> 6;
  if (lane == 0) wsum[w] = x;
  __syncthreads();
  if (threadIdx.x < 16) {
    int y = wsum[threadIdx.x];
#pragma unroll
    for (int off = 8; off; off >>= 1) y += __shfl_down(y, off);
    if (threadIdx.x == 0) partial[blockIdx.x] = y;
  }
}

// scan pass 2: exclusive scan of NB partials (single wave, looped)
__global__ void scan_small_kernel(int* __restrict__ partial, int NB) {
  int lane = threadIdx.x;  // 64 threads
  int carry = 0;
  for (int base = 0; base < NB; base += 64) {
    int x = (base + lane < NB) ? partial[base + lane] : 0;
    int incl = x;
#pragma unroll
    for (int off = 1; off < 64; off <<= 1) {
      int y = __shfl_up(incl, off);
      if (lane >= off) incl += y;
    }
    int tot = __shfl(incl, 63);
    if (base + lane < NB) partial[base + lane] = incl - x + carry;
    carry += tot;
  }
}

// scan pass 3: per-chunk scan + chunk offset -> row_start, cursor
__global__ __launch_bounds__(1024) void scan_apply_kernel(const int* __restrict__ counts,
                                                          const int* __restrict__ partial,
                                                          int* __restrict__ row_start,
                                                          int* __restrict__ cursor,
                                                          int N, int E) {
  __shared__ int wtot[16];
  __shared__ int woff[16];
  int i = blockIdx.x * 1024 + threadIdx.x;
  int lane = threadIdx.x & 63, w = threadIdx.x >> 6;
  int x = (i < N) ? counts[i] : 0;
  int incl = x;
#pragma unroll
  for (int off = 1; off < 64; off <<= 1) {
    int y = __shfl_up(incl, off);
    if (lane >= off) incl += y;
  }
  if (lane == 63) wtot[w] = incl;
  __syncthreads();
  if (w == 0 && lane < 16) {
    int wv = wtot[lane];
    int wincl = wv;
#pragma unroll
    for (int off = 1; off < 16; off <<= 1) {
      int y = __shfl_up(wincl, off);
      if (lane >= off) wincl += y;
    }
    woff[lane] = wincl - wv;
  }
  __syncthreads();
  int excl = incl - x + woff[w] + partial[blockIdx.x];
  if (i < N) { row_start[i] = excl; cursor[i] = excl; }  // cursor==counts alias:
  if (i == 0) row_start[N] = E;                          // own-idx read-then-write, safe
}

__global__ void csr_bucket_kernel(const int* __restrict__ src,
                                  const int* __restrict__ dst,
                                  const float* __restrict__ he,
                                  int* __restrict__ cursor,
                                  int* __restrict__ srcs_sorted,
                                  float* __restrict__ he_sorted, int E) {
  int e = blockIdx.x * blockDim.x + threadIdx.x;
  if (e >= E) return;
  int pos = atomicAdd(&cursor[dst[e]], 1);
  srcs_sorted[pos] = src[e];
  he_sorted[pos] = he[e];
}

// ---- t=0 only: hv0 fp32 -> hb fp16 (later rounds: fused epilogue emits hb) ----
__global__ void convert_kernel(const float* __restrict__ hv,
                               _Float16* __restrict__ hb, int total4) {
  int i = blockIdx.x * blockDim.x + threadIdx.x;
  if (i >= total4) return;
  float4 v = *reinterpret_cast<const float4*>(hv + (size_t)i * 4);
  h4 o;
  o.a = (_Float16)v.x; o.b = (_Float16)v.y; o.c = (_Float16)v.z; o.d = (_Float16)v.w;
  *reinterpret_cast<h4*>(hb + (size_t)i * 4) = o;
}

// ---- per round: gather s[v]=sum hb[src], g[v]=sum he (no atomics);
//      write xbF fragment-interleaved ----
__global__ __launch_bounds__(256) void prep_kernel(const _Float16* __restrict__ hb,
                                                   const int* __restrict__ row_start,
                                                   const int* __restrict__ srcs_sorted,
                                                   const float* __restrict__ he_sorted,
                                                   _Float16* __restrict__ xbF,
                                                   float* __restrict__ deg,
                                                   float* __restrict__ g, int N) {
  int w = threadIdx.x >> 6;
  int lane = threadIdx.x & 63;
  int v = blockIdx.x * 4 + w;
  if (v >= N) return;
  int r0 = row_start[v];
  int r1 = row_start[v + 1];
  float ax = 0.f, ay = 0.f, hes = 0.f;
  for (int base = r0; base < r1; base += 64) {
    int nn = min(64, r1 - base);
    int myv = (lane < nn) ? srcs_sorted[base + lane] : 0;
    hes += (lane < nn) ? he_sorted[base + lane] : 0.f;
    int j = 0;
    for (; j + 4 <= nn; j += 4) {
      int s0 = __shfl(myv, j + 0), s1 = __shfl(myv, j + 1);
      int s2 = __shfl(myv, j + 2), s3 = __shfl(myv, j + 3);
      h2 u0 = *reinterpret_cast<const h2*>(hb + (size_t)s0 * 128 + lane * 2);
      h2 u1 = *reinterpret_cast<const h2*>(hb + (size_t)s1 * 128 + lane * 2);
      h2 u2 = *reinterpret_cast<const h2*>(hb + (size_t)s2 * 128 + lane * 2);
      h2 u3 = *reinterpret_cast<const h2*>(hb + (size_t)s3 * 128 + lane * 2);
      ax += (float)u0.x + (float)u1.x + (float)u2.x + (float)u3.x;
      ay += (float)u0.y + (float)u1.y + (float)u2.y + (float)u3.y;
    }
    for (; j < nn; ++j) {
      int sv = __shfl(myv, j);
      h2 u = *reinterpret_cast<const h2*>(hb + (size_t)sv * 128 + lane * 2);
      ax += (float)u.x; ay += (float)u.y;
    }
  }
#pragma unroll
  for (int off = 32; off; off >>= 1) hes += __shfl_xor(hes, off);
  float d = (float)(r1 - r0);
  h2 hu = *reinterpret_cast<const h2*>(hb + (size_t)v * 128 + lane * 2);
  h2 dh; dh.x = (_Float16)(d * (float)hu.x); dh.y = (_Float16)(d * (float)hu.y);
  h2 ss; ss.x = (_Float16)ax; ss.y = (_Float16)ay;
  int mt = v >> 4, lrv = v & 15;
  _Float16* xmt = xbF + (size_t)mt * 12 * 512;
  auto store2 = [&](int c, h2 val) {
    int k0c = c >> 5, lkg = (c >> 3) & 3, kin = c & 7;
    _Float16* p = xmt + (size_t)k0c * 512 + (lkg * 16 + lrv) * 8 + kin;
    *reinterpret_cast<h2*>(p) = val;
  };
  store2(lane * 2, dh);            // plane 0: deg*h   (x-cols 0..127)
  store2(128 + lane * 2, ss);      // plane 1: s       (x-cols 128..255)
  store2(256 + lane * 2, hu);      // plane 2: h       (x-cols 256..383)
  if (lane == 0) { deg[v] = d; g[v] = hes; }
}

// ---- fused GEMM (fp16 MFMA, B in LDS) + GRU gate epilogue ----
// Block = 8 waves x col-group (blockIdx.y); covers 16 m-tiles (wave owns 2).
// B slice (96KB) staged in two 48KB LDS sweeps -> 3 blocks/CU, B fetched
// from L2 once per block (was: once per wave -> 1.2GB L2, the r12 limiter).
// ds_read pattern lane*16B contiguous = 2-way bank aliasing (free).
__global__ __launch_bounds__(512) void fused_gemm_gate_kernel(
    const _Float16* __restrict__ xbF,
    const _Float16* __restrict__ wbigF,
    const float* __restrict__ deg, const float* __restrict__ gv,
    const float* __restrict__ cvec,
    const float* __restrict__ bih, const float* __restrict__ bhh,
    const float* __restrict__ hv_in, float* __restrict__ hv_out,
    _Float16* __restrict__ hb_out, int M) {
  __shared__ _Float16 ldsB[6 * 8 * 512];  // 48 KB, one sweep
  int tid = threadIdx.x;
  int wave = tid >> 6, lane = tid & 63;
  int Mt = (M + 15) >> 4;
  int cg = blockIdx.y;                    // col-group: jj in [cg*32, cg*32+32)
  int mt0 = blockIdx.x * 16 + wave * 2;   // wave's two m-tiles
  int mta = min(mt0, Mt - 1);
  int mtb = min(mt0 + 1, Mt - 1);

  f32x4 acc[2][2][4];  // [m][j][p]
#pragma unroll
  for (int m = 0; m < 2; ++m)
#pragma unroll
    for (int j = 0; j < 2; ++j)
#pragma unroll
      for (int p = 0; p < 4; ++p) acc[m][j][p] = (f32x4){0.f, 0.f, 0.f, 0.f};

  const _Float16* apa = xbF + (size_t)mta * 12 * 512 + lane * 8;
  const _Float16* apb = xbF + (size_t)mtb * 12 * 512 + lane * 8;

  for (int s = 0; s < 2; ++s) {
    if (s) __syncthreads();              // sweep-0 reads done before restage
#pragma unroll
    for (int i = 0; i < 6; ++i) {        // stage 6x8KB chunks; 16B/thread each
      int k0c = s * 6 + i;
      const float4* srcp =
          reinterpret_cast<const float4*>(wbigF + (size_t)(k0c * 4 + cg) * 8 * 512) + tid;
      reinterpret_cast<float4*>(ldsB + i * 4096)[tid] = *srcp;
    }
    __syncthreads();
#pragma unroll
    for (int i = 0; i < 6; ++i) {
      int k0c = s * 6 + i;
      f16x8 a0 = *reinterpret_cast<const f16x8*>(apa + (size_t)k0c * 512);
      f16x8 a1 = *reinterpret_cast<const f16x8*>(apb + (size_t)k0c * 512);
#pragma unroll
      for (int p = 0; p < 4; ++p) {
#pragma unroll
        for (int j = 0; j < 2; ++j) {
          f16x8 b = *reinterpret_cast<const f16x8*>(ldsB + (i * 8 + p * 2 + j) * 512 + lane * 8);
          acc[0][j][p] = __builtin_amdgcn_mfma_f32_16x16x32_f16(a0, b, acc[0][j][p], 0, 0, 0);
          acc[1][j][p] = __builtin_amdgcn_mfma_f32_16x16x32_f16(a1, b, acc[1][j][p], 0, 0, 0);
        }
      }
    }
  }

  // epilogue (no barriers below): C layout col=lane&15, row=(lane>>4)*4+reg
  int lr = lane & 15;
#pragma unroll
  for (int m = 0; m < 2; ++m) {
    int mt = mt0 + m;
    if (mt >= Mt) continue;
    float dr[4], gr[4];
#pragma unroll
    for (int reg = 0; reg < 4; ++reg) {
      int v = min(mt * 16 + (lane >> 4) * 4 + reg, M - 1);
      dr[reg] = deg[v]; gr[reg] = gv[v];
    }
#pragma unroll
    for (int j = 0; j < 2; ++j) {
      int jj = cg * 32 + j * 16 + lr;          // 0..127
      float cv0 = cvec[jj], cv1 = cvec[128 + jj], cv2 = cvec[256 + jj];
      float cg0 = cvec[384 + jj], cg1 = cvec[512 + jj], cg2 = cvec[640 + jj];
      float b0 = bih[jj] + bhh[jj];
      float b1 = bih[128 + jj] + bhh[128 + jj];
      float b2 = bih[256 + jj];
      float b3 = bhh[256 + jj];
#pragma unroll
      for (int reg = 0; reg < 4; ++reg) {
        int v = mt * 16 + (lane >> 4) * 4 + reg;
        if (v >= M) continue;
        float pre_r = acc[m][j][0][reg] + dr[reg] * cv0 + gr[reg] * cg0 + b0;
        float pre_z = acc[m][j][1][reg] + dr[reg] * cv1 + gr[reg] * cg1 + b1;
        float i_n   = acc[m][j][2][reg] + dr[reg] * cv2 + gr[reg] * cg2 + b2;
        float h_n   = acc[m][j][3][reg] + b3;
        float r = fsig(pre_r);
        float z = fsig(pre_z);
        float n = ftanh(i_n + r * h_n);
        float h = hv_in[(size_t)v * 128 + jj];
        float hp = (1.0f - z) * n + z * h;
        hv_out[(size_t)v * 128 + jj] = hp;
        hb_out[(size_t)v * 128 + jj] = (_Float16)hp;  // next round's fp16 state
      }
    }
  }
}

extern "C" void kernel_launch(void* const* d_in, const int* in_sizes, int n_in,
                              void* d_out, int out_size, void* d_ws, size_t ws_size,
                              hipStream_t stream) {
  const float* hv0  = (const float*)d_in[0];
  const float* he   = (const float*)d_in[1];
  const int*   src  = (const int*)d_in[2];
  const int*   dst  = (const int*)d_in[3];
  const float* Wmsg = (const float*)d_in[4];
  const float* bmsg = (const float*)d_in[5];
  const float* Wih  = (const float*)d_in[6];
  const float* Whh  = (const float*)d_in[7];
  const float* bih  = (const float*)d_in[8];
  const float* bhh  = (const float*)d_in[9];

  int N = in_sizes[0] / 128;
  int E = in_sizes[1];
  int T = in_sizes[4] / (256 * 257);
  int Mt = (N + 15) / 16;
  int NB = (N + 1023) / 1024;

  size_t off = 0;
  auto alloc = [&](size_t bytes) { size_t o = off; off += (bytes + 15) & ~(size_t)15; return o; };
  size_t o_hb   = alloc((size_t)N * 128 * 2);
  size_t o_xb   = alloc((size_t)Mt * 12 * 512 * 2);
  size_t o_deg  = alloc((size_t)N * 4);
  size_t o_g    = alloc((size_t)N * 4);
  size_t o_cv   = alloc((size_t)T * 768 * 4);
  size_t o_wb   = alloc((size_t)T * 512 * 384 * 2);
  size_t o_rs   = alloc((size_t)(N + 1) * 4);
  size_t o_ss   = alloc((size_t)E * 4);
  size_t o_he   = alloc((size_t)E * 4);
  size_t o_pt   = alloc((size_t)NB * 4);
  if (ws_size < off) return;  // clean failure instead of OOB crash

  char* wsb = (char*)d_ws;
  _Float16* hb     = (_Float16*)(wsb + o_hb);
  _Float16* xbF    = (_Float16*)(wsb + o_xb);
  float* deg       = (float*)(wsb + o_deg);
  float* g         = (float*)(wsb + o_g);
  float* cvec      = (float*)(wsb + o_cv);
  _Float16* wbigF  = (_Float16*)(wsb + o_wb);
  int* row_start   = (int*)(wsb + o_rs);
  int* srcs_sorted = (int*)(wsb + o_ss);
  float* he_sorted = (float*)(wsb + o_he);
  int* partial     = (int*)(wsb + o_pt);
  int* cursor      = (int*)xbF;  // scratch during CSR build only
  float* out = (float*)d_out;

  {
    dim3 gb((386 + 63) / 64, 512, T);
    build_wbig_kernel<<<gb, 64, 0, stream>>>(Wih, Whh, Wmsg, bmsg, wbigF, cvec);
  }

  hipMemsetAsync(cursor, 0, (size_t)N * sizeof(int), stream);
  csr_count_kernel<<<(E + 255) / 256, 256, 0, stream>>>(dst, cursor, E);
  scan_reduce_kernel<<<NB, 1024, 0, stream>>>(cursor, partial, N);
  scan_small_kernel<<<1, 64, 0, stream>>>(partial, NB);
  scan_apply_kernel<<<NB, 1024, 0, stream>>>(cursor, partial, row_start, cursor, N, E);
  csr_bucket_kernel<<<(E + 255) / 256, 256, 0, stream>>>(src, dst, he, cursor,
                                                         srcs_sorted, he_sorted, E);

  for (int t = 0; t < T; ++t) {
    const float* hv_in = (t == 0) ? hv0 : out;
    if (t == 0) {
      int total4 = N * 128 / 4;
      convert_kernel<<<(total4 + 255) / 256, 256, 0, stream>>>(hv_in, hb, total4);
    }
    prep_kernel<<<(N + 3) / 4, 256, 0, stream>>>(hb, row_start, srcs_sorted, he_sorted,
                                                 xbF, deg, g, N);
    dim3 gf((Mt + 15) / 16, 4);
    fused_gemm_gate_kernel<<<gf, 512, 0, stream>>>(
        xbF, wbigF + (size_t)t * 512 * 384, deg, g, cvec + (size_t)t * 768,
        bih + (size_t)t * 384, bhh + (size_t)t * 384, hv_in, out, hb, N);
  }
}